// Round 10
// baseline (463.354 us; speedup 1.0000x reference)
//
#include <hip/hip_runtime.h>
#include <hip/hip_bf16.h>
#include <math.h>

typedef __hip_bfloat16 bf16;
typedef unsigned short ushort;
typedef unsigned int uint;
static __device__ __forceinline__ float b2f(bf16 x){ return __bfloat162float(x); }

// flag-aware load: isbf!=0 -> buffer is bf16, else fp32
static __device__ __forceinline__ float ldf(const void* p, int i, int isbf){
    return isbf ? b2f(((const bf16*)p)[i]) : ((const float*)p)[i];
}
// order-preserving float<->uint coding (works for negatives; no NaNs in data)
static __device__ __forceinline__ uint fcode(float v){
    uint u = __float_as_uint(v);
    return (u & 0x80000000u) ? ~u : (u | 0x80000000u);
}
static __device__ __forceinline__ float fdecode(uint c){
    uint u = (c & 0x80000000u) ? (c & 0x7FFFFFFFu) : ~c;
    return __uint_as_float(u);
}

#define NN    4096
#define FEAT0 500
#define DIN   512
#define NH    256
#define KL1   3072
#define KL2   2304
#define KL3   1728
#define EDGE_CAP 786432u

typedef __attribute__((ext_vector_type(8)))  short v8s;   // 8 bf16 in 4 VGPRs
typedef __attribute__((ext_vector_type(16))) float v16f;  // 32x32 MFMA acc

// ---------------- init + per-tensor dtype autodetect -----------------------
struct DtIn { const void* p[19]; int n[19]; };
__global__ void k_initall(DtIn a, unsigned* flags, float* degA, uint* maxU, float* sums,
        unsigned* ecnt, unsigned* maxd2){
    int i = blockIdx.x*256 + threadIdx.x;
    if (i < NN)  degA[i] = 1.0f;              // self-loop
    if (i < 768){ maxU[i] = 0x007FFFFFu; sums[i] = 0.f; }   // fcode(-inf)
    if (i == 0){ ecnt[0]=0u; ecnt[1]=0u; ecnt[2]=0u; maxd2[0]=0u; }
    if (blockIdx.x == 0 && threadIdx.x < 19){
        int t = threadIdx.x;
        const unsigned short* h = (const unsigned short*)a.p[t];
        int n = a.n[t]; if (n > 256) n = 256;
        int isbf = 1;
        for (int j = 0; j < n; j++){
            unsigned e = ((unsigned)h[j] >> 7) & 0xFFu;
            if (e >= 135u) isbf = 0;          // |v|>=64 impossible for true bf16 data here
        }
        flags[t] = (unsigned)isbf;
    }
}

// ---------------- pos MLP + concat; write bf16 Xb, sq(from bf16) -----------
__global__ __launch_bounds__(512) void k_posconcat(const void* __restrict__ feature,
        const void* __restrict__ img, const void* __restrict__ Wpos, const void* __restrict__ bpos,
        const unsigned* __restrict__ dflag, ushort* __restrict__ Xb, float* __restrict__ sq){
    int f_feat = (int)dflag[0], f_img = (int)dflag[1], f_wp = (int)dflag[2], f_bp = (int)dflag[3];
    int row = blockIdx.x, t = threadIdx.x;
    float v;
    if (t < FEAT0) v = ldf(feature, row*FEAT0 + t, f_feat);
    else {
        int c = t - FEAT0;
        float acc = ldf(bpos, c, f_bp);
        #pragma unroll
        for (int d = 0; d < 6; d++) acc += ldf(img, row*6+d, f_img) * ldf(Wpos, d*12+c, f_wp);
        v = fmaxf(acc, 0.f);
    }
    bf16 vb = __float2bfloat16(v);
    Xb[row*DIN + t] = __bfloat16_as_ushort(vb);
    float vr = b2f(vb);                 // sq of rounded vector -> d2 exact for bf16 X
    __shared__ float red[512];
    red[t] = vr*vr;
    __syncthreads();
    for (int s = 256; s > 0; s >>= 1){ if (t < s) red[t] += red[t+s]; __syncthreads(); }
    if (t == 0) sq[row] = red[0];
}

// ---------------- convert W1/W2/W3 to bf16 (once) --------------------------
__global__ void k_wconv(const void* __restrict__ W1, const void* __restrict__ W2,
        const void* __restrict__ W3, const unsigned* __restrict__ dflag, ushort* __restrict__ Wb){
    int i0 = blockIdx.x*1024 + threadIdx.x*4;
    #pragma unroll
    for (int j = 0; j < 4; j++){
        int idx = i0 + j;
        float v;
        if (idx < 131072)       v = ldf(W1, idx,          (int)dflag[4]);
        else if (idx < 196608)  v = ldf(W2, idx - 131072, (int)dflag[6]);
        else                    v = ldf(W3, idx - 196608, (int)dflag[8]);
        Wb[idx] = __bfloat16_as_ushort(__float2bfloat16(v));
    }
}

// ---------------- Gram via MFMA, 64x64 tile, LDS-staged --------------------
// PASS 1: global max d2 + per-tile min d2 (r>c). PASS 2: edges, but a tile
// whose min d2 >= t is skipped entirely (exact bound; for this data all skip).
template<int PASS>
__global__ __launch_bounds__(256) void k_gram(const ushort* __restrict__ Xb,
        const float* __restrict__ sq, unsigned* __restrict__ maxd2,
        float* __restrict__ tmin, unsigned* __restrict__ ecnt,
        unsigned* __restrict__ edges, float* __restrict__ deg){
    int rb = blockIdx.x, cb = blockIdx.y;
    if (cb > rb) return;                  // lower triangle only (uniform exit)
    if (PASS == 2){
        float tthr0 = 0.5f * __uint_as_float(maxd2[0]);
        if (tmin[rb*64 + cb] >= tthr0) return;   // uniform: no edge in this tile
    }
    __shared__ __align__(16) ushort As[64*64];
    __shared__ __align__(16) ushort Bs[64*64];
    int tid = threadIdx.x;
    int lane = tid & 63, wv = tid >> 6;
    int wwr = wv >> 1, wwc = wv & 1;
    int l31 = lane & 31, hi = lane >> 5;

    int row0 = tid >> 3,       g0 = tid & 7;
    int row1 = (tid+256) >> 3, g1 = tid & 7;
    const size_t baseA = (size_t)rb*64*DIN;
    const size_t baseB = (size_t)cb*64*DIN;
    int d0 = row0*64 + ((g0^(row0&7))<<3);
    int d1 = row1*64 + ((g1^(row1&7))<<3);

    float4 a0p = *(const float4*)(Xb + baseA + (size_t)row0*DIN + g0*8);
    float4 a1p = *(const float4*)(Xb + baseA + (size_t)row1*DIN + g1*8);
    float4 b0p = *(const float4*)(Xb + baseB + (size_t)row0*DIN + g0*8);
    float4 b1p = *(const float4*)(Xb + baseB + (size_t)row1*DIN + g1*8);

    v16f acc = {};
    int ra0 = (wwr*32 + l31)*64;
    int rb0 = (wwc*32 + l31)*64;
    int fr7a = (wwr*32 + l31) & 7;
    int fr7b = (wwc*32 + l31) & 7;

    for (int c = 0; c < 8; c++){
        __syncthreads();
        *(float4*)&As[d0] = a0p;  *(float4*)&As[d1] = a1p;
        *(float4*)&Bs[d0] = b0p;  *(float4*)&Bs[d1] = b1p;
        __syncthreads();
        if (c < 7){
            int k0 = (c+1)*64;
            a0p = *(const float4*)(Xb + baseA + (size_t)row0*DIN + k0 + g0*8);
            a1p = *(const float4*)(Xb + baseA + (size_t)row1*DIN + k0 + g1*8);
            b0p = *(const float4*)(Xb + baseB + (size_t)row0*DIN + k0 + g0*8);
            b1p = *(const float4*)(Xb + baseB + (size_t)row1*DIN + k0 + g1*8);
        }
        #pragma unroll
        for (int ks = 0; ks < 4; ks++){
            int gq = ks*2 + hi;
            v8s a = *(const v8s*)&As[ra0 + ((gq^fr7a)<<3)];
            v8s b = *(const v8s*)&Bs[rb0 + ((gq^fr7b)<<3)];
            acc = __builtin_amdgcn_mfma_f32_32x32x16_bf16(a, b, acc, 0, 0, 0);
        }
    }

    int rbase = rb*64 + wwr*32 + 4*hi;
    int col   = cb*64 + wwc*32 + l31;
    float sqc = sq[col];
    if (PASS == 1){
        float m = 0.f, mn = INFINITY;
        #pragma unroll
        for (int i = 0; i < 16; i++){
            int r = rbase + (i&3) + 8*(i>>2);
            float d2 = sq[r] + sqc - 2.f*acc[i];
            if (r != col) m = fmaxf(m, d2);
            if (r > col)  mn = fminf(mn, d2);
        }
        #pragma unroll
        for (int off = 32; off >= 1; off >>= 1){
            m  = fmaxf(m,  __shfl_down(m,  off));
            mn = fminf(mn, __shfl_down(mn, off));
        }
        __shared__ float wmin[4];
        if (lane == 0){
            atomicMax(maxd2, __float_as_uint(fmaxf(m, 0.f)));
            wmin[wv] = mn;
        }
        __syncthreads();
        if (tid == 0)
            tmin[rb*64 + cb] = fminf(fminf(wmin[0], wmin[1]), fminf(wmin[2], wmin[3]));
    } else {
        float tthr = 0.5f * __uint_as_float(maxd2[0]);
        #pragma unroll
        for (int i = 0; i < 16; i++){
            int r = rbase + (i&3) + 8*(i>>2);
            float d2 = sq[r] + sqc - 2.f*acc[i];
            if (r > col && d2 < tthr){
                unsigned idx = atomicAdd(ecnt, 1u);
                if (idx < EDGE_CAP){
                    edges[idx] = ((unsigned)r << 16) | (unsigned)col;  // dst<<16|src
                    atomicAdd(&deg[r], 1.0f);
                }
            }
        }
    }
}

// ---------------- X @ W via MFMA (bf16), fused dis-scale + self-agg --------
__global__ __launch_bounds__(256) void k_xw(const ushort* __restrict__ Ab,
        const ushort* __restrict__ Wb, const float* __restrict__ deg,
        float* __restrict__ XW, float* __restrict__ AGG, int M, int K){
    int rb = blockIdx.x, cb = blockIdx.y;     // (M/64, 4)
    __shared__ __align__(16) ushort As[64*64];
    __shared__ __align__(16) ushort Bs[64*64]; // Bs[n*64+kk] = W[k0+kk][cb*64+n]
    int tid = threadIdx.x, lane = tid & 63, wv = tid >> 6;
    int wwr = wv >> 1, wwc = wv & 1;
    int l31 = lane & 31, hi = lane >> 5;

    int arow0 = tid >> 3, ag = tid & 7;
    int arow1 = arow0 + 32;
    int da0 = arow0*64 + ((ag^(arow0&7))<<3);
    int da1 = arow1*64 + ((ag^(arow1&7))<<3);
    const size_t baseA = (size_t)rb*64*K;
    int kr = tid >> 2, ng = tid & 3;          // B: thread covers W[kr][ng*16..+15]

    float4 a0p = *(const float4*)(Ab + baseA + (size_t)arow0*K + ag*8);
    float4 a1p = *(const float4*)(Ab + baseA + (size_t)arow1*K + ag*8);
    float4 b0p = *(const float4*)(Wb + (size_t)kr*NH + cb*64 + ng*16);
    float4 b1p = *(const float4*)(Wb + (size_t)kr*NH + cb*64 + ng*16 + 8);

    v16f acc = {};
    int ra0 = (wwr*32 + l31)*64;
    int rb0 = (wwc*32 + l31)*64;
    int fr7a = (wwr*32 + l31) & 7;
    int fr7b = (wwc*32 + l31) & 7;
    int kg = kr >> 3, k7 = kr & 7;

    int NC = K >> 6;
    for (int c = 0; c < NC; c++){
        __syncthreads();
        *(float4*)&As[da0] = a0p; *(float4*)&As[da1] = a1p;
        const ushort* bw0 = (const ushort*)&b0p;
        const ushort* bw1 = (const ushort*)&b1p;
        #pragma unroll
        for (int j = 0; j < 8; j++){
            int nn = ng*16 + j;
            Bs[nn*64 + ((kg^(nn&7))<<3) + k7] = bw0[j];
        }
        #pragma unroll
        for (int j = 0; j < 8; j++){
            int nn = ng*16 + 8 + j;
            Bs[nn*64 + ((kg^(nn&7))<<3) + k7] = bw1[j];
        }
        __syncthreads();
        if (c + 1 < NC){
            int k0 = (c+1)*64;
            a0p = *(const float4*)(Ab + baseA + (size_t)arow0*K + k0 + ag*8);
            a1p = *(const float4*)(Ab + baseA + (size_t)arow1*K + k0 + ag*8);
            b0p = *(const float4*)(Wb + (size_t)(k0+kr)*NH + cb*64 + ng*16);
            b1p = *(const float4*)(Wb + (size_t)(k0+kr)*NH + cb*64 + ng*16 + 8);
        }
        #pragma unroll
        for (int ks = 0; ks < 4; ks++){
            int gq = ks*2 + hi;
            v8s a = *(const v8s*)&As[ra0 + ((gq^fr7a)<<3)];
            v8s b = *(const v8s*)&Bs[rb0 + ((gq^fr7b)<<3)];
            acc = __builtin_amdgcn_mfma_f32_32x32x16_bf16(a, b, acc, 0, 0, 0);
        }
    }
    int n  = cb*64 + wwc*32 + l31;
    int mb = rb*64 + wwr*32 + 4*hi;
    #pragma unroll
    for (int i = 0; i < 16; i++){
        int m = mb + (i&3) + 8*(i>>2);
        float dis = 1.0f / sqrtf(deg[m]);
        float v = acc[i] * dis;
        size_t o = (size_t)m*NH + n;
        XW[o] = v; AGG[o] = v;
    }
}

// agg[dst] += xw'[src] for each edge
__global__ __launch_bounds__(256) void k_edgeagg(const unsigned* __restrict__ edges,
        const unsigned* __restrict__ ecnt, int slot,
        const float* __restrict__ xwp, float* __restrict__ agg){
    unsigned E = ecnt[slot]; if (E > EDGE_CAP) E = EDGE_CAP;
    int t = threadIdx.x;
    for (unsigned e = blockIdx.x; e < E; e += gridDim.x){
        unsigned ed = edges[e];
        int dst = ed >> 16, src = ed & 0xFFFFu;
        atomicAdd(&agg[dst*NH + t], xwp[src*NH + t]);
    }
}

// x = relu(dis*agg + b); fused scorer: s1 = x.Wn ; z = x.Wr + bs
__global__ __launch_bounds__(256) void k_gcnscore(const float* __restrict__ AGG,
        const float* __restrict__ deg, const void* __restrict__ b,
        const void* __restrict__ Wn, const void* __restrict__ Wr, const void* __restrict__ bs,
        const unsigned* __restrict__ fb, const unsigned* __restrict__ fWn,
        const unsigned* __restrict__ fWr, const unsigned* __restrict__ fbs,
        float* __restrict__ Xn, float* __restrict__ s1, float* __restrict__ z){
    int row = blockIdx.x, t = threadIdx.x;
    float dis = 1.0f / sqrtf(deg[row]);
    float xn = fmaxf(fmaf(dis, AGG[row*NH + t], ldf(b, t, (int)fb[0])), 0.f);
    Xn[row*NH + t] = xn;
    float a  = xn * ldf(Wn, t, (int)fWn[0]);
    float bb = xn * ldf(Wr, t, (int)fWr[0]);
    for (int off = 32; off >= 1; off >>= 1){ a += __shfl_down(a, off); bb += __shfl_down(bb, off); }
    __shared__ float ra[4], rbv[4];
    int w = t >> 6;
    if ((t & 63) == 0){ ra[w] = a; rbv[w] = bb; }
    __syncthreads();
    if (t == 0){
        s1[row] = ra[0]+ra[1]+ra[2]+ra[3];
        z[row]  = rbv[0]+rbv[1]+rbv[2]+rbv[3] + ldf(bs, 0, (int)fbs[0]);
    }
}

// ---------------- fused: scoredge + radix top-k select + efilter -----------
// Single block. z/rank live in LDS; edges are tiny (worst case still correct).
__global__ __launch_bounds__(1024) void k_select(const float* __restrict__ z,
        const float* __restrict__ s1, int N, int k,
        const unsigned* __restrict__ eIn, unsigned* __restrict__ ecnt, int slotCur,
        unsigned* __restrict__ eOut, int slotOut,
        int* __restrict__ perm, float* __restrict__ svals,
        float* __restrict__ degN, int Nnext){
    __shared__ float zsh[4096];
    __shared__ int   rnk[4096];
    __shared__ uint  hist[256];
    __shared__ uint  sh[4];    // 0:prefix 1:rem 2:selCnt 3:eqCnt
    int t = threadIdx.x;
    for (int i = t; i < N; i += 1024){ zsh[i] = z[i]; rnk[i] = -1; }
    for (int i = t; i < Nnext; i += 1024) degN[i] = 1.0f;
    if (t == 0){ sh[0] = 0u; sh[1] = (uint)k; sh[2] = 0u; sh[3] = 0u; }
    __syncthreads();
    // scoredge: z[dst] += s1[src]
    unsigned E = ecnt[slotCur]; if (E > EDGE_CAP) E = EDGE_CAP;
    for (unsigned e = t; e < E; e += 1024){
        unsigned ed = eIn[e];
        atomicAdd(&zsh[ed >> 16], s1[ed & 0xFFFFu]);
    }
    __syncthreads();
    // radix select (descending) on fcode(zsh)
    uint prefmask = 0u;
    for (int pass = 0; pass < 4; pass++){
        int shift = 24 - 8*pass;
        if (t < 256) hist[t] = 0u;
        __syncthreads();
        uint prefix = sh[0];
        for (int i = t; i < N; i += 1024){
            uint ky = fcode(zsh[i]);
            if ((ky & prefmask) == prefix) atomicAdd(&hist[(ky >> shift) & 255u], 1u);
        }
        __syncthreads();
        if (t == 0){
            uint rem = sh[1], cum = 0u;
            for (int bidx = 255; bidx >= 0; bidx--){
                uint c = hist[bidx];
                if (cum + c >= rem){ sh[0] = prefix | ((uint)bidx << shift); sh[1] = rem - cum; break; }
                cum += c;
            }
        }
        prefmask |= (0xFFu << shift);
        __syncthreads();
    }
    uint T = sh[0], rem = sh[1];
    for (int i = t; i < N; i += 1024){
        uint ky = fcode(zsh[i]);
        bool sel = (ky > T);
        if (!sel && ky == T){ uint e = atomicAdd(&sh[3], 1u); sel = (e < rem); }
        if (sel){
            uint r = atomicAdd(&sh[2], 1u);
            perm[r] = i;
            svals[r] = tanhf(zsh[i]);
            rnk[i] = (int)r;
        }
    }
    __syncthreads();
    // efilter: surviving edges renumbered into eOut + next-layer degree
    if (slotOut >= 0){
        for (unsigned e = t; e < E; e += 1024){
            unsigned ed = eIn[e];
            int nd = rnk[ed >> 16], ns = rnk[ed & 0xFFFFu];
            if (nd >= 0 && ns >= 0){
                unsigned idx = atomicAdd(&ecnt[slotOut], 1u);
                if (idx < EDGE_CAP){
                    eOut[idx] = ((unsigned)nd << 16) | (unsigned)ns;
                    atomicAdd(&degN[nd], 1.0f);
                }
            }
        }
    }
}

// ---------------- fused pool + readout: Pb (bf16) + col max/sum atomics ----
__global__ __launch_bounds__(256) void k_poolread(const float* __restrict__ Xn,
        const int* __restrict__ perm, const float* __restrict__ svals,
        ushort* __restrict__ Pb, int k, uint* __restrict__ maxU,
        float* __restrict__ sums, int layer){
    int b = blockIdx.x, t = threadIdx.x;
    float m = -INFINITY, s = 0.f;
    for (int r = b; r < k; r += 64){
        int p = perm[r];
        float v = Xn[p*NH + t] * svals[r];
        Pb[r*NH + t] = __bfloat16_as_ushort(__float2bfloat16(v));
        m = fmaxf(m, v); s += v;
    }
    atomicMax(&maxU[layer*NH + t], fcode(m));
    atomicAdd(&sums[layer*NH + t], s);
}

__global__ void k_writeout(const uint* __restrict__ maxU, const float* __restrict__ sums,
        float* __restrict__ out, float i1, float i2, float i3){
    int t = threadIdx.x;
    if (blockIdx.x == 0)
        out[t] = fdecode(maxU[t]) + fdecode(maxU[NH + t]) + fdecode(maxU[2*NH + t]);
    else
        out[NH + t] = sums[t]*i1 + sums[NH + t]*i2 + sums[2*NH + t]*i3;
}

// =======================================================================
extern "C" void kernel_launch(void* const* d_in, const int* in_sizes, int n_in,
                              void* d_out, int out_size, void* d_ws, size_t ws_size,
                              hipStream_t stream)
{
    const void* feature = d_in[0];
    const void* img     = d_in[1];
    const void* Wpos    = d_in[2];
    const void* bpos    = d_in[3];
    const void* W1 = d_in[4];  const void* b1 = d_in[5];
    const void* W2 = d_in[6];  const void* b2 = d_in[7];
    const void* W3 = d_in[8];  const void* b3 = d_in[9];
    const void* Wr1 = d_in[10]; const void* Wn1 = d_in[11]; const void* bs1 = d_in[12];
    const void* Wr2 = d_in[13]; const void* Wn2 = d_in[14]; const void* bs2 = d_in[15];
    const void* Wr3 = d_in[16]; const void* Wn3 = d_in[17]; const void* bs3 = d_in[18];

    char* w = (char*)d_ws;
    auto alloc = [&](size_t bytes)->char*{ char* p = w; w += (bytes + 255) & ~(size_t)255; return p; };
    ushort*   Xb    = (ushort*)  alloc((size_t)NN*DIN*2);   // 4 MB
    float*    Xn    = (float*)   alloc((size_t)NN*NH*4);    // 4 MB
    float*    XW    = (float*)   alloc((size_t)NN*NH*4);    // 4 MB
    float*    AGG   = (float*)   alloc((size_t)NN*NH*4);    // 4 MB
    ushort*   Pb    = (ushort*)  alloc((size_t)KL1*NH*2);   // 1.5 MB pooled bf16
    ushort*   Wb    = (ushort*)  alloc((size_t)262144*2);   // 0.5 MB W1|W2|W3 bf16
    unsigned* E0    = (unsigned*)alloc((size_t)EDGE_CAP*4); // 3 MB
    unsigned* E1    = (unsigned*)alloc((size_t)EDGE_CAP*4); // 3 MB
    float*    tmin  = (float*)   alloc(4096*4);             // per-tile min d2
    float*    sq    = (float*)   alloc(NN*4);
    float*    degA  = (float*)   alloc(NN*4);
    float*    degB  = (float*)   alloc(NN*4);
    float*    s1    = (float*)   alloc(NN*4);
    float*    z     = (float*)   alloc(NN*4);
    int*      perm  = (int*)     alloc(NN*4);
    float*    svals = (float*)   alloc(NN*4);
    unsigned* ecnt  = (unsigned*)alloc(256);
    unsigned* maxd2 = (unsigned*)alloc(256);
    unsigned* dflag = (unsigned*)alloc(256);
    uint*     maxU  = (uint*)    alloc(768*4);
    float*    sums  = (float*)   alloc(768*4);
    (void)ws_size;

    DtIn da;
    for (int i = 0; i < 19; i++){ da.p[i] = d_in[i]; da.n[i] = in_sizes[i]; }
    k_initall<<<16, 256, 0, stream>>>(da, dflag, degA, maxU, sums, ecnt, maxd2);
    k_posconcat<<<NN, 512, 0, stream>>>(feature, img, Wpos, bpos, dflag, Xb, sq);
    k_wconv<<<256, 256, 0, stream>>>(W1, W2, W3, dflag, Wb);
    dim3 gg(64, 64);
    k_gram<1><<<gg, 256, 0, stream>>>(Xb, sq, maxd2, tmin, ecnt, E0, degA);
    k_gram<2><<<gg, 256, 0, stream>>>(Xb, sq, maxd2, tmin, ecnt, E0, degA);

    // ---------------- layer 1 (N=4096 -> k=3072) ----------------
    k_xw<<<dim3(64,4), 256, 0, stream>>>(Xb, Wb, degA, XW, AGG, NN, DIN);
    k_edgeagg<<<512, 256, 0, stream>>>(E0, ecnt, 0, XW, AGG);
    k_gcnscore<<<NN, 256, 0, stream>>>(AGG, degA, b1, Wn1, Wr1, bs1,
            dflag+5, dflag+11, dflag+10, dflag+12, Xn, s1, z);
    k_select<<<1, 1024, 0, stream>>>(z, s1, NN, KL1, E0, ecnt, 0, E1, 1,
            perm, svals, degB, KL1);
    k_poolread<<<64, 256, 0, stream>>>(Xn, perm, svals, Pb, KL1, maxU, sums, 0);

    // ---------------- layer 2 (N=3072 -> k=2304) ----------------
    k_xw<<<dim3(48,4), 256, 0, stream>>>(Pb, Wb + 131072, degB, XW, AGG, KL1, NH);
    k_edgeagg<<<512, 256, 0, stream>>>(E1, ecnt, 1, XW, AGG);
    k_gcnscore<<<KL1, 256, 0, stream>>>(AGG, degB, b2, Wn2, Wr2, bs2,
            dflag+7, dflag+14, dflag+13, dflag+15, Xn, s1, z);
    k_select<<<1, 1024, 0, stream>>>(z, s1, KL1, KL2, E1, ecnt, 1, E0, 2,
            perm, svals, degA, KL2);
    k_poolread<<<64, 256, 0, stream>>>(Xn, perm, svals, Pb, KL2, maxU, sums, 1);

    // ---------------- layer 3 (N=2304 -> k=1728) ----------------
    k_xw<<<dim3(36,4), 256, 0, stream>>>(Pb, Wb + 196608, degA, XW, AGG, KL2, NH);
    k_edgeagg<<<512, 256, 0, stream>>>(E0, ecnt, 2, XW, AGG);
    k_gcnscore<<<KL2, 256, 0, stream>>>(AGG, degA, b3, Wn3, Wr3, bs3,
            dflag+9, dflag+17, dflag+16, dflag+18, Xn, s1, z);
    k_select<<<1, 1024, 0, stream>>>(z, s1, KL2, KL3, E0, ecnt, 2, (unsigned*)nullptr, -1,
            perm, svals, degB, 0);
    k_poolread<<<64, 256, 0, stream>>>(Xn, perm, svals, Pb, KL3, maxU, sums, 2);

    k_writeout<<<2, 256, 0, stream>>>(maxU, sums, (float*)d_out,
            1.0f/KL1, 1.0f/KL2, 1.0f/KL3);
}

// Round 11
// 381.793 us; speedup vs baseline: 1.2136x; 1.2136x over previous
//
#include <hip/hip_runtime.h>
#include <hip/hip_bf16.h>
#include <math.h>

typedef __hip_bfloat16 bf16;
typedef unsigned short ushort;
typedef unsigned int uint;
static __device__ __forceinline__ float b2f(bf16 x){ return __bfloat162float(x); }

// flag-aware load: isbf!=0 -> buffer is bf16, else fp32
static __device__ __forceinline__ float ldf(const void* p, int i, int isbf){
    return isbf ? b2f(((const bf16*)p)[i]) : ((const float*)p)[i];
}
// order-preserving float<->uint coding (works for negatives; no NaNs in data)
static __device__ __forceinline__ uint fcode(float v){
    uint u = __float_as_uint(v);
    return (u & 0x80000000u) ? ~u : (u | 0x80000000u);
}
static __device__ __forceinline__ float fdecode(uint c){
    uint u = (c & 0x80000000u) ? (c & 0x7FFFFFFFu) : ~c;
    return __uint_as_float(u);
}

#define NN    4096
#define FEAT0 500
#define DIN   512
#define NH    256
#define KL1   3072
#define KL2   2304
#define KL3   1728
#define EDGE_CAP 786432u

typedef __attribute__((ext_vector_type(8)))  short v8s;   // 8 bf16 in 4 VGPRs
typedef __attribute__((ext_vector_type(16))) float v16f;  // 32x32 MFMA acc

// ---------------- init + per-tensor dtype autodetect -----------------------
struct DtIn { const void* p[19]; int n[19]; };
__global__ void k_initall(DtIn a, unsigned* flags, float* degA, uint* maxU, float* sums,
        unsigned* ecnt, float* tmax, float* tmin){
    int i = blockIdx.x*256 + threadIdx.x;
    if (i < NN)  degA[i] = 1.0f;              // self-loop
    if (i < 768){ maxU[i] = 0x007FFFFFu; sums[i] = 0.f; }   // fcode(-inf)
    if (i < 4096){ tmax[i] = 0.f; tmin[i] = INFINITY; }
    if (i == 0){ ecnt[0]=0u; ecnt[1]=0u; ecnt[2]=0u; }
    if (blockIdx.x == 0 && threadIdx.x < 19){
        int t = threadIdx.x;
        const unsigned short* h = (const unsigned short*)a.p[t];
        int n = a.n[t]; if (n > 256) n = 256;
        int isbf = 1;
        for (int j = 0; j < n; j++){
            unsigned e = ((unsigned)h[j] >> 7) & 0xFFu;
            if (e >= 135u) isbf = 0;          // |v|>=64 impossible for true bf16 data here
        }
        flags[t] = (unsigned)isbf;
    }
}

// ---------------- pos MLP + concat + W-convert (fused) ---------------------
// blocks [0,NN): posconcat row; blocks [NN,NN+64): convert W1|W2|W3 -> bf16
__global__ __launch_bounds__(512) void k_prep(const void* __restrict__ feature,
        const void* __restrict__ img, const void* __restrict__ Wpos, const void* __restrict__ bpos,
        const void* __restrict__ W1, const void* __restrict__ W2, const void* __restrict__ W3,
        const unsigned* __restrict__ dflag, ushort* __restrict__ Xb, float* __restrict__ sq,
        ushort* __restrict__ Wb){
    int row = blockIdx.x, t = threadIdx.x;
    if (row < NN){
        int f_feat = (int)dflag[0], f_img = (int)dflag[1], f_wp = (int)dflag[2], f_bp = (int)dflag[3];
        float v;
        if (t < FEAT0) v = ldf(feature, row*FEAT0 + t, f_feat);
        else {
            int c = t - FEAT0;
            float acc = ldf(bpos, c, f_bp);
            #pragma unroll
            for (int d = 0; d < 6; d++) acc += ldf(img, row*6+d, f_img) * ldf(Wpos, d*12+c, f_wp);
            v = fmaxf(acc, 0.f);
        }
        bf16 vb = __float2bfloat16(v);
        Xb[row*DIN + t] = __bfloat16_as_ushort(vb);
        float vr = b2f(vb);                 // sq of rounded vector -> d2 exact for bf16 X
        __shared__ float red[512];
        red[t] = vr*vr;
        __syncthreads();
        for (int s = 256; s > 0; s >>= 1){ if (t < s) red[t] += red[t+s]; __syncthreads(); }
        if (t == 0) sq[row] = red[0];
    } else {
        int i0 = ((row - NN)*512 + t)*8;
        #pragma unroll
        for (int j = 0; j < 8; j++){
            int idx = i0 + j;
            float v;
            if (idx < 131072)       v = ldf(W1, idx,          (int)dflag[4]);
            else if (idx < 196608)  v = ldf(W2, idx - 131072, (int)dflag[6]);
            else                    v = ldf(W3, idx - 196608, (int)dflag[8]);
            Wb[idx] = __bfloat16_as_ushort(__float2bfloat16(v));
        }
    }
}

// ---------------- Gram via MFMA, 64x64 tile, LDS-staged --------------------
// PASS 1: per-tile max/min d2 -> tmax/tmin (plain stores, no atomics).
// PASS 2: t = 0.5*max(tmax) (exact, order-invariant); skip tile if tmin>=t.
template<int PASS>
__global__ __launch_bounds__(256) void k_gram(const ushort* __restrict__ Xb,
        const float* __restrict__ sq, float* __restrict__ tmax, float* __restrict__ tmin,
        unsigned* __restrict__ ecnt, unsigned* __restrict__ edges, float* __restrict__ deg){
    int rb = blockIdx.x, cb = blockIdx.y;
    if (cb > rb) return;                  // lower triangle only (uniform exit)
    int tid = threadIdx.x;
    float tthr = 0.f;
    if (PASS == 2){
        __shared__ float redt[256];
        float m = 0.f;
        for (int i = tid; i < 4096; i += 256) m = fmaxf(m, tmax[i]);
        redt[tid] = m; __syncthreads();
        for (int s = 128; s > 0; s >>= 1){
            if (tid < s) redt[tid] = fmaxf(redt[tid], redt[tid+s]);
            __syncthreads();
        }
        tthr = 0.5f * redt[0];
        if (tmin[rb*64 + cb] >= tthr) return;   // uniform: no edge in this tile
    }
    __shared__ __align__(16) ushort As[64*64];
    __shared__ __align__(16) ushort Bs[64*64];
    int lane = tid & 63, wv = tid >> 6;
    int wwr = wv >> 1, wwc = wv & 1;
    int l31 = lane & 31, hi = lane >> 5;

    int row0 = tid >> 3,       g0 = tid & 7;
    int row1 = (tid+256) >> 3, g1 = tid & 7;
    const size_t baseA = (size_t)rb*64*DIN;
    const size_t baseB = (size_t)cb*64*DIN;
    int d0 = row0*64 + ((g0^(row0&7))<<3);
    int d1 = row1*64 + ((g1^(row1&7))<<3);

    float4 a0p = *(const float4*)(Xb + baseA + (size_t)row0*DIN + g0*8);
    float4 a1p = *(const float4*)(Xb + baseA + (size_t)row1*DIN + g1*8);
    float4 b0p = *(const float4*)(Xb + baseB + (size_t)row0*DIN + g0*8);
    float4 b1p = *(const float4*)(Xb + baseB + (size_t)row1*DIN + g1*8);

    v16f acc = {};
    int ra0 = (wwr*32 + l31)*64;
    int rb0 = (wwc*32 + l31)*64;
    int fr7a = (wwr*32 + l31) & 7;
    int fr7b = (wwc*32 + l31) & 7;

    for (int c = 0; c < 8; c++){
        __syncthreads();
        *(float4*)&As[d0] = a0p;  *(float4*)&As[d1] = a1p;
        *(float4*)&Bs[d0] = b0p;  *(float4*)&Bs[d1] = b1p;
        __syncthreads();
        if (c < 7){
            int k0 = (c+1)*64;
            a0p = *(const float4*)(Xb + baseA + (size_t)row0*DIN + k0 + g0*8);
            a1p = *(const float4*)(Xb + baseA + (size_t)row1*DIN + k0 + g1*8);
            b0p = *(const float4*)(Xb + baseB + (size_t)row0*DIN + k0 + g0*8);
            b1p = *(const float4*)(Xb + baseB + (size_t)row1*DIN + k0 + g1*8);
        }
        #pragma unroll
        for (int ks = 0; ks < 4; ks++){
            int gq = ks*2 + hi;
            v8s a = *(const v8s*)&As[ra0 + ((gq^fr7a)<<3)];
            v8s b = *(const v8s*)&Bs[rb0 + ((gq^fr7b)<<3)];
            acc = __builtin_amdgcn_mfma_f32_32x32x16_bf16(a, b, acc, 0, 0, 0);
        }
    }

    int rbase = rb*64 + wwr*32 + 4*hi;
    int col   = cb*64 + wwc*32 + l31;
    float sqc = sq[col];
    if (PASS == 1){
        float m = 0.f, mn = INFINITY;
        #pragma unroll
        for (int i = 0; i < 16; i++){
            int r = rbase + (i&3) + 8*(i>>2);
            float d2 = sq[r] + sqc - 2.f*acc[i];
            if (r != col) m = fmaxf(m, d2);
            if (r > col)  mn = fminf(mn, d2);
        }
        #pragma unroll
        for (int off = 32; off >= 1; off >>= 1){
            m  = fmaxf(m,  __shfl_down(m,  off));
            mn = fminf(mn, __shfl_down(mn, off));
        }
        __shared__ float wmax[4], wmin[4];
        if (lane == 0){ wmax[wv] = m; wmin[wv] = mn; }
        __syncthreads();
        if (tid == 0){
            tmax[rb*64 + cb] = fmaxf(fmaxf(wmax[0], wmax[1]), fmaxf(wmax[2], wmax[3]));
            tmin[rb*64 + cb] = fminf(fminf(wmin[0], wmin[1]), fminf(wmin[2], wmin[3]));
        }
    } else {
        #pragma unroll
        for (int i = 0; i < 16; i++){
            int r = rbase + (i&3) + 8*(i>>2);
            float d2 = sq[r] + sqc - 2.f*acc[i];
            if (r > col && d2 < tthr){
                unsigned idx = atomicAdd(ecnt, 1u);
                if (idx < EDGE_CAP){
                    edges[idx] = ((unsigned)r << 16) | (unsigned)col;  // dst<<16|src
                    atomicAdd(&deg[r], 1.0f);
                }
            }
        }
    }
}

// ---------------- X @ W via MFMA (bf16), raw output ------------------------
__global__ __launch_bounds__(256) void k_xw(const ushort* __restrict__ Ab,
        const ushort* __restrict__ Wb, float* __restrict__ XW, int M, int K){
    int rb = blockIdx.x, cb = blockIdx.y;     // (M/64, 4)
    __shared__ __align__(16) ushort As[64*64];
    __shared__ __align__(16) ushort Bs[64*64]; // Bs[n*64+kk] = W[k0+kk][cb*64+n]
    int tid = threadIdx.x, lane = tid & 63, wv = tid >> 6;
    int wwr = wv >> 1, wwc = wv & 1;
    int l31 = lane & 31, hi = lane >> 5;

    int arow0 = tid >> 3, ag = tid & 7;
    int arow1 = arow0 + 32;
    int da0 = arow0*64 + ((ag^(arow0&7))<<3);
    int da1 = arow1*64 + ((ag^(arow1&7))<<3);
    const size_t baseA = (size_t)rb*64*K;
    int kr = tid >> 2, ng = tid & 3;          // B: thread covers W[kr][ng*16..+15]

    float4 a0p = *(const float4*)(Ab + baseA + (size_t)arow0*K + ag*8);
    float4 a1p = *(const float4*)(Ab + baseA + (size_t)arow1*K + ag*8);
    float4 b0p = *(const float4*)(Wb + (size_t)kr*NH + cb*64 + ng*16);
    float4 b1p = *(const float4*)(Wb + (size_t)kr*NH + cb*64 + ng*16 + 8);

    v16f acc = {};
    int ra0 = (wwr*32 + l31)*64;
    int rb0 = (wwc*32 + l31)*64;
    int fr7a = (wwr*32 + l31) & 7;
    int fr7b = (wwc*32 + l31) & 7;
    int kg = kr >> 3, k7 = kr & 7;

    int NC = K >> 6;
    for (int c = 0; c < NC; c++){
        __syncthreads();
        *(float4*)&As[da0] = a0p; *(float4*)&As[da1] = a1p;
        const ushort* bw0 = (const ushort*)&b0p;
        const ushort* bw1 = (const ushort*)&b1p;
        #pragma unroll
        for (int j = 0; j < 8; j++){
            int nn = ng*16 + j;
            Bs[nn*64 + ((kg^(nn&7))<<3) + k7] = bw0[j];
        }
        #pragma unroll
        for (int j = 0; j < 8; j++){
            int nn = ng*16 + 8 + j;
            Bs[nn*64 + ((kg^(nn&7))<<3) + k7] = bw1[j];
        }
        __syncthreads();
        if (c + 1 < NC){
            int k0 = (c+1)*64;
            a0p = *(const float4*)(Ab + baseA + (size_t)arow0*K + k0 + ag*8);
            a1p = *(const float4*)(Ab + baseA + (size_t)arow1*K + k0 + ag*8);
            b0p = *(const float4*)(Wb + (size_t)(k0+kr)*NH + cb*64 + ng*16);
            b1p = *(const float4*)(Wb + (size_t)(k0+kr)*NH + cb*64 + ng*16 + 8);
        }
        #pragma unroll
        for (int ks = 0; ks < 4; ks++){
            int gq = ks*2 + hi;
            v8s a = *(const v8s*)&As[ra0 + ((gq^fr7a)<<3)];
            v8s b = *(const v8s*)&Bs[rb0 + ((gq^fr7b)<<3)];
            acc = __builtin_amdgcn_mfma_f32_32x32x16_bf16(a, b, acc, 0, 0, 0);
        }
    }
    int n  = cb*64 + wwc*32 + l31;
    int mb = rb*64 + wwr*32 + 4*hi;
    #pragma unroll
    for (int i = 0; i < 16; i++){
        int m = mb + (i&3) + 8*(i>>2);
        XW[(size_t)m*NH + n] = acc[i];
    }
}

// ---- fused GCN finish: edge-scan aggregation + relu + scorer --------------
// acc = dis[row]*xw[row] + sum_{edges dst==row} dis[src]*xw[src]
// xn = relu(dis[row]*acc + b); s1 = xn.Wn; z = xn.Wr + bs
__global__ __launch_bounds__(256) void k_gcnscore(const float* __restrict__ XW,
        const unsigned* __restrict__ edges, const unsigned* __restrict__ ecnt, int slot,
        const float* __restrict__ deg, const void* __restrict__ b,
        const void* __restrict__ Wn, const void* __restrict__ Wr, const void* __restrict__ bs,
        const unsigned* __restrict__ fb, const unsigned* __restrict__ fWn,
        const unsigned* __restrict__ fWr, const unsigned* __restrict__ fbs,
        float* __restrict__ Xn, float* __restrict__ s1, float* __restrict__ z){
    int row = blockIdx.x, t = threadIdx.x;
    __shared__ unsigned eL[256];
    __shared__ unsigned Esh;
    if (t == 0){ unsigned E0 = ecnt[slot]; Esh = (E0 > EDGE_CAP) ? EDGE_CAP : E0; }
    __syncthreads();
    unsigned E = Esh;
    float disr = 1.0f / sqrtf(deg[row]);
    float acc = disr * XW[row*NH + t];          // self term
    for (unsigned base = 0; base < E; base += 256){
        unsigned nchunk = E - base; if (nchunk > 256) nchunk = 256;
        __syncthreads();
        if (t < nchunk) eL[t] = edges[base + t];
        __syncthreads();
        for (unsigned j = 0; j < nchunk; j++){
            unsigned ed = eL[j];
            if ((int)(ed >> 16) == row){
                int src = ed & 0xFFFFu;
                acc += (1.0f / sqrtf(deg[src])) * XW[src*NH + t];
            }
        }
    }
    float xn = fmaxf(fmaf(disr, acc, ldf(b, t, (int)fb[0])), 0.f);
    Xn[row*NH + t] = xn;
    float a  = xn * ldf(Wn, t, (int)fWn[0]);
    float bb = xn * ldf(Wr, t, (int)fWr[0]);
    for (int off = 32; off >= 1; off >>= 1){ a += __shfl_down(a, off); bb += __shfl_down(bb, off); }
    __shared__ float ra[4], rbv[4];
    int w = t >> 6;
    if ((t & 63) == 0){ ra[w] = a; rbv[w] = bb; }
    __syncthreads();
    if (t == 0){
        s1[row] = ra[0]+ra[1]+ra[2]+ra[3];
        z[row]  = rbv[0]+rbv[1]+rbv[2]+rbv[3] + ldf(bs, 0, (int)fbs[0]);
    }
}

// ---------------- fused: scoredge + radix top-k select + efilter -----------
__global__ __launch_bounds__(1024) void k_select(const float* __restrict__ z,
        const float* __restrict__ s1, int N, int k,
        const unsigned* __restrict__ eIn, unsigned* __restrict__ ecnt, int slotCur,
        unsigned* __restrict__ eOut, int slotOut,
        int* __restrict__ perm, float* __restrict__ svals,
        float* __restrict__ degN, int Nnext){
    __shared__ float zsh[4096];
    __shared__ int   rnk[4096];
    __shared__ uint  hist[256];
    __shared__ uint  sh[4];    // 0:prefix 1:rem 2:selCnt 3:eqCnt
    int t = threadIdx.x;
    for (int i = t; i < N; i += 1024){ zsh[i] = z[i]; rnk[i] = -1; }
    for (int i = t; i < Nnext; i += 1024) degN[i] = 1.0f;
    if (t == 0){ sh[0] = 0u; sh[1] = (uint)k; sh[2] = 0u; sh[3] = 0u; }
    __syncthreads();
    unsigned E = ecnt[slotCur]; if (E > EDGE_CAP) E = EDGE_CAP;
    for (unsigned e = t; e < E; e += 1024){
        unsigned ed = eIn[e];
        atomicAdd(&zsh[ed >> 16], s1[ed & 0xFFFFu]);
    }
    __syncthreads();
    uint prefmask = 0u;
    for (int pass = 0; pass < 4; pass++){
        int shift = 24 - 8*pass;
        if (t < 256) hist[t] = 0u;
        __syncthreads();
        uint prefix = sh[0];
        for (int i = t; i < N; i += 1024){
            uint ky = fcode(zsh[i]);
            if ((ky & prefmask) == prefix) atomicAdd(&hist[(ky >> shift) & 255u], 1u);
        }
        __syncthreads();
        if (t == 0){
            uint rem = sh[1], cum = 0u;
            for (int bidx = 255; bidx >= 0; bidx--){
                uint c = hist[bidx];
                if (cum + c >= rem){ sh[0] = prefix | ((uint)bidx << shift); sh[1] = rem - cum; break; }
                cum += c;
            }
        }
        prefmask |= (0xFFu << shift);
        __syncthreads();
    }
    uint T = sh[0], rem = sh[1];
    for (int i = t; i < N; i += 1024){
        uint ky = fcode(zsh[i]);
        bool sel = (ky > T);
        if (!sel && ky == T){ uint e = atomicAdd(&sh[3], 1u); sel = (e < rem); }
        if (sel){
            uint r = atomicAdd(&sh[2], 1u);
            perm[r] = i;
            svals[r] = tanhf(zsh[i]);
            rnk[i] = (int)r;
        }
    }
    __syncthreads();
    if (slotOut >= 0){
        for (unsigned e = t; e < E; e += 1024){
            unsigned ed = eIn[e];
            int nd = rnk[ed >> 16], ns = rnk[ed & 0xFFFFu];
            if (nd >= 0 && ns >= 0){
                unsigned idx = atomicAdd(&ecnt[slotOut], 1u);
                if (idx < EDGE_CAP){
                    eOut[idx] = ((unsigned)nd << 16) | (unsigned)ns;
                    atomicAdd(&degN[nd], 1.0f);
                }
            }
        }
    }
}

// ---------------- fused pool + readout: Pb (bf16) + col max/sum atomics ----
__global__ __launch_bounds__(256) void k_poolread(const float* __restrict__ Xn,
        const int* __restrict__ perm, const float* __restrict__ svals,
        ushort* __restrict__ Pb, int k, uint* __restrict__ maxU,
        float* __restrict__ sums, int layer){
    int b = blockIdx.x, t = threadIdx.x;
    float m = -INFINITY, s = 0.f;
    for (int r = b; r < k; r += 64){
        int p = perm[r];
        float v = Xn[p*NH + t] * svals[r];
        Pb[r*NH + t] = __bfloat16_as_ushort(__float2bfloat16(v));
        m = fmaxf(m, v); s += v;
    }
    atomicMax(&maxU[layer*NH + t], fcode(m));
    atomicAdd(&sums[layer*NH + t], s);
}

__global__ void k_writeout(const uint* __restrict__ maxU, const float* __restrict__ sums,
        float* __restrict__ out, float i1, float i2, float i3){
    int t = threadIdx.x;
    if (blockIdx.x == 0)
        out[t] = fdecode(maxU[t]) + fdecode(maxU[NH + t]) + fdecode(maxU[2*NH + t]);
    else
        out[NH + t] = sums[t]*i1 + sums[NH + t]*i2 + sums[2*NH + t]*i3;
}

// =======================================================================
extern "C" void kernel_launch(void* const* d_in, const int* in_sizes, int n_in,
                              void* d_out, int out_size, void* d_ws, size_t ws_size,
                              hipStream_t stream)
{
    const void* feature = d_in[0];
    const void* img     = d_in[1];
    const void* Wpos    = d_in[2];
    const void* bpos    = d_in[3];
    const void* W1 = d_in[4];  const void* b1 = d_in[5];
    const void* W2 = d_in[6];  const void* b2 = d_in[7];
    const void* W3 = d_in[8];  const void* b3 = d_in[9];
    const void* Wr1 = d_in[10]; const void* Wn1 = d_in[11]; const void* bs1 = d_in[12];
    const void* Wr2 = d_in[13]; const void* Wn2 = d_in[14]; const void* bs2 = d_in[15];
    const void* Wr3 = d_in[16]; const void* Wn3 = d_in[17]; const void* bs3 = d_in[18];

    char* w = (char*)d_ws;
    auto alloc = [&](size_t bytes)->char*{ char* p = w; w += (bytes + 255) & ~(size_t)255; return p; };
    ushort*   Xb    = (ushort*)  alloc((size_t)NN*DIN*2);   // 4 MB
    float*    Xn    = (float*)   alloc((size_t)NN*NH*4);    // 4 MB
    float*    XW    = (float*)   alloc((size_t)NN*NH*4);    // 4 MB
    ushort*   Pb    = (ushort*)  alloc((size_t)KL1*NH*2);   // 1.5 MB pooled bf16
    ushort*   Wb    = (ushort*)  alloc((size_t)262144*2);   // 0.5 MB W1|W2|W3 bf16
    unsigned* E0    = (unsigned*)alloc((size_t)EDGE_CAP*4); // 3 MB
    unsigned* E1    = (unsigned*)alloc((size_t)EDGE_CAP*4); // 3 MB
    float*    tmax  = (float*)   alloc(4096*4);             // per-tile max d2
    float*    tmin  = (float*)   alloc(4096*4);             // per-tile min d2 (r>c)
    float*    sq    = (float*)   alloc(NN*4);
    float*    degA  = (float*)   alloc(NN*4);
    float*    degB  = (float*)   alloc(NN*4);
    float*    s1    = (float*)   alloc(NN*4);
    float*    z     = (float*)   alloc(NN*4);
    int*      perm  = (int*)     alloc(NN*4);
    float*    svals = (float*)   alloc(NN*4);
    unsigned* ecnt  = (unsigned*)alloc(256);
    unsigned* dflag = (unsigned*)alloc(256);
    uint*     maxU  = (uint*)    alloc(768*4);
    float*    sums  = (float*)   alloc(768*4);
    (void)ws_size;

    DtIn da;
    for (int i = 0; i < 19; i++){ da.p[i] = d_in[i]; da.n[i] = in_sizes[i]; }
    k_initall<<<16, 256, 0, stream>>>(da, dflag, degA, maxU, sums, ecnt, tmax, tmin);
    k_prep<<<NN + 64, 512, 0, stream>>>(feature, img, Wpos, bpos, W1, W2, W3,
            dflag, Xb, sq, Wb);
    dim3 gg(64, 64);
    k_gram<1><<<gg, 256, 0, stream>>>(Xb, sq, tmax, tmin, ecnt, E0, degA);
    k_gram<2><<<gg, 256, 0, stream>>>(Xb, sq, tmax, tmin, ecnt, E0, degA);

    // ---------------- layer 1 (N=4096 -> k=3072) ----------------
    k_xw<<<dim3(64,4), 256, 0, stream>>>(Xb, Wb, XW, NN, DIN);
    k_gcnscore<<<NN, 256, 0, stream>>>(XW, E0, ecnt, 0, degA, b1, Wn1, Wr1, bs1,
            dflag+5, dflag+11, dflag+10, dflag+12, Xn, s1, z);
    k_select<<<1, 1024, 0, stream>>>(z, s1, NN, KL1, E0, ecnt, 0, E1, 1,
            perm, svals, degB, KL1);
    k_poolread<<<64, 256, 0, stream>>>(Xn, perm, svals, Pb, KL1, maxU, sums, 0);

    // ---------------- layer 2 (N=3072 -> k=2304) ----------------
    k_xw<<<dim3(48,4), 256, 0, stream>>>(Pb, Wb + 131072, XW, KL1, NH);
    k_gcnscore<<<KL1, 256, 0, stream>>>(XW, E1, ecnt, 1, degB, b2, Wn2, Wr2, bs2,
            dflag+7, dflag+14, dflag+13, dflag+15, Xn, s1, z);
    k_select<<<1, 1024, 0, stream>>>(z, s1, KL1, KL2, E1, ecnt, 1, E0, 2,
            perm, svals, degA, KL2);
    k_poolread<<<64, 256, 0, stream>>>(Xn, perm, svals, Pb, KL2, maxU, sums, 1);

    // ---------------- layer 3 (N=2304 -> k=1728) ----------------
    k_xw<<<dim3(36,4), 256, 0, stream>>>(Pb, Wb + 196608, XW, KL2, NH);
    k_gcnscore<<<KL2, 256, 0, stream>>>(XW, E0, ecnt, 2, degA, b3, Wn3, Wr3, bs3,
            dflag+9, dflag+17, dflag+16, dflag+18, Xn, s1, z);
    k_select<<<1, 1024, 0, stream>>>(z, s1, KL2, KL3, E0, ecnt, 2, (unsigned*)nullptr, -1,
            perm, svals, degB, 0);
    k_poolread<<<64, 256, 0, stream>>>(Xn, perm, svals, Pb, KL3, maxU, sums, 2);

    k_writeout<<<2, 256, 0, stream>>>(maxU, sums, (float*)d_out,
            1.0f/KL1, 1.0f/KL2, 1.0f/KL3);
}

// Round 12
// 306.441 us; speedup vs baseline: 1.5121x; 1.2459x over previous
//
#include <hip/hip_runtime.h>
#include <hip/hip_bf16.h>
#include <math.h>

typedef __hip_bfloat16 bf16;
typedef unsigned short ushort;
typedef unsigned int uint;
typedef unsigned long long ull;
static __device__ __forceinline__ float b2f(bf16 x){ return __bfloat162float(x); }

// flag-aware load: isbf!=0 -> buffer is bf16, else fp32
static __device__ __forceinline__ float ldf(const void* p, int i, int isbf){
    return isbf ? b2f(((const bf16*)p)[i]) : ((const float*)p)[i];
}
// order-preserving float<->uint coding (works for negatives; no NaNs in data)
static __device__ __forceinline__ uint fcode(float v){
    uint u = __float_as_uint(v);
    return (u & 0x80000000u) ? ~u : (u | 0x80000000u);
}
static __device__ __forceinline__ float fdecode(uint c){
    uint u = (c & 0x80000000u) ? (c & 0x7FFFFFFFu) : ~c;
    return __uint_as_float(u);
}

#define NN    4096
#define FEAT0 500
#define DIN   512
#define NH    256
#define KL1   3072
#define KL2   2304
#define KL3   1728
#define EDGE_CAP 786432u

typedef __attribute__((ext_vector_type(8)))  short v8s;   // 8 bf16 in 4 VGPRs
typedef __attribute__((ext_vector_type(16))) float v16f;  // 32x32 MFMA acc

// ---------------- init + per-tensor dtype autodetect -----------------------
struct DtIn { const void* p[19]; int n[19]; };
__global__ void k_initall(DtIn a, unsigned* flags, float* degA, uint* maxU, float* sums,
        unsigned* ecnt, float* tmax, float* tmin){
    int i = blockIdx.x*256 + threadIdx.x;
    if (i < NN)  degA[i] = 1.0f;              // self-loop
    if (i < 768){ maxU[i] = 0x007FFFFFu; sums[i] = 0.f; }   // fcode(-inf)
    if (i < 4096){ tmax[i] = 0.f; tmin[i] = INFINITY; }
    if (i == 0){ ecnt[0]=0u; ecnt[1]=0u; ecnt[2]=0u; }
    if (blockIdx.x == 0 && threadIdx.x < 19){
        int t = threadIdx.x;
        const unsigned short* h = (const unsigned short*)a.p[t];
        int n = a.n[t]; if (n > 256) n = 256;
        int isbf = 1;
        for (int j = 0; j < n; j++){
            unsigned e = ((unsigned)h[j] >> 7) & 0xFFu;
            if (e >= 135u) isbf = 0;          // |v|>=64 impossible for true bf16 data here
        }
        flags[t] = (unsigned)isbf;
    }
}

// ---------------- pos MLP + concat + W-convert (fused) ---------------------
__global__ __launch_bounds__(512) void k_prep(const void* __restrict__ feature,
        const void* __restrict__ img, const void* __restrict__ Wpos, const void* __restrict__ bpos,
        const void* __restrict__ W1, const void* __restrict__ W2, const void* __restrict__ W3,
        const unsigned* __restrict__ dflag, ushort* __restrict__ Xb, float* __restrict__ sq,
        ushort* __restrict__ Wb){
    int row = blockIdx.x, t = threadIdx.x;
    if (row < NN){
        int f_feat = (int)dflag[0], f_img = (int)dflag[1], f_wp = (int)dflag[2], f_bp = (int)dflag[3];
        float v;
        if (t < FEAT0) v = ldf(feature, row*FEAT0 + t, f_feat);
        else {
            int c = t - FEAT0;
            float acc = ldf(bpos, c, f_bp);
            #pragma unroll
            for (int d = 0; d < 6; d++) acc += ldf(img, row*6+d, f_img) * ldf(Wpos, d*12+c, f_wp);
            v = fmaxf(acc, 0.f);
        }
        bf16 vb = __float2bfloat16(v);
        Xb[row*DIN + t] = __bfloat16_as_ushort(vb);
        float vr = b2f(vb);                 // sq of rounded vector -> d2 exact for bf16 X
        __shared__ float red[512];
        red[t] = vr*vr;
        __syncthreads();
        for (int s = 256; s > 0; s >>= 1){ if (t < s) red[t] += red[t+s]; __syncthreads(); }
        if (t == 0) sq[row] = red[0];
    } else {
        int i0 = ((row - NN)*512 + t)*8;
        #pragma unroll
        for (int j = 0; j < 8; j++){
            int idx = i0 + j;
            float v;
            if (idx < 131072)       v = ldf(W1, idx,          (int)dflag[4]);
            else if (idx < 196608)  v = ldf(W2, idx - 131072, (int)dflag[6]);
            else                    v = ldf(W3, idx - 196608, (int)dflag[8]);
            Wb[idx] = __bfloat16_as_ushort(__float2bfloat16(v));
        }
    }
}

// ---------------- Gram via MFMA, 64x64 tile, LDS-staged --------------------
// PASS 1: per-tile max/min d2 -> tmax/tmin (plain stores, no atomics).
// PASS 2: t = 0.5*max(tmax) (exact, order-invariant); skip tile if tmin>=t.
template<int PASS>
__global__ __launch_bounds__(256) void k_gram(const ushort* __restrict__ Xb,
        const float* __restrict__ sq, float* __restrict__ tmax, float* __restrict__ tmin,
        unsigned* __restrict__ ecnt, unsigned* __restrict__ edges, float* __restrict__ deg){
    int rb = blockIdx.x, cb = blockIdx.y;
    if (cb > rb) return;                  // lower triangle only (uniform exit)
    int tid = threadIdx.x;
    float tthr = 0.f;
    if (PASS == 2){
        __shared__ float redt[256];
        float m = 0.f;
        for (int i = tid; i < 4096; i += 256) m = fmaxf(m, tmax[i]);
        redt[tid] = m; __syncthreads();
        for (int s = 128; s > 0; s >>= 1){
            if (tid < s) redt[tid] = fmaxf(redt[tid], redt[tid+s]);
            __syncthreads();
        }
        tthr = 0.5f * redt[0];
        if (tmin[rb*64 + cb] >= tthr) return;   // uniform: no edge in this tile
    }
    __shared__ __align__(16) ushort As[64*64];
    __shared__ __align__(16) ushort Bs[64*64];
    int lane = tid & 63, wv = tid >> 6;
    int wwr = wv >> 1, wwc = wv & 1;
    int l31 = lane & 31, hi = lane >> 5;

    int row0 = tid >> 3,       g0 = tid & 7;
    int row1 = (tid+256) >> 3, g1 = tid & 7;
    const size_t baseA = (size_t)rb*64*DIN;
    const size_t baseB = (size_t)cb*64*DIN;
    int d0 = row0*64 + ((g0^(row0&7))<<3);
    int d1 = row1*64 + ((g1^(row1&7))<<3);

    float4 a0p = *(const float4*)(Xb + baseA + (size_t)row0*DIN + g0*8);
    float4 a1p = *(const float4*)(Xb + baseA + (size_t)row1*DIN + g1*8);
    float4 b0p = *(const float4*)(Xb + baseB + (size_t)row0*DIN + g0*8);
    float4 b1p = *(const float4*)(Xb + baseB + (size_t)row1*DIN + g1*8);

    v16f acc = {};
    int ra0 = (wwr*32 + l31)*64;
    int rb0 = (wwc*32 + l31)*64;
    int fr7a = (wwr*32 + l31) & 7;
    int fr7b = (wwc*32 + l31) & 7;

    for (int c = 0; c < 8; c++){
        __syncthreads();
        *(float4*)&As[d0] = a0p;  *(float4*)&As[d1] = a1p;
        *(float4*)&Bs[d0] = b0p;  *(float4*)&Bs[d1] = b1p;
        __syncthreads();
        if (c < 7){
            int k0 = (c+1)*64;
            a0p = *(const float4*)(Xb + baseA + (size_t)row0*DIN + k0 + g0*8);
            a1p = *(const float4*)(Xb + baseA + (size_t)row1*DIN + k0 + g1*8);
            b0p = *(const float4*)(Xb + baseB + (size_t)row0*DIN + k0 + g0*8);
            b1p = *(const float4*)(Xb + baseB + (size_t)row1*DIN + k0 + g1*8);
        }
        #pragma unroll
        for (int ks = 0; ks < 4; ks++){
            int gq = ks*2 + hi;
            v8s a = *(const v8s*)&As[ra0 + ((gq^fr7a)<<3)];
            v8s b = *(const v8s*)&Bs[rb0 + ((gq^fr7b)<<3)];
            acc = __builtin_amdgcn_mfma_f32_32x32x16_bf16(a, b, acc, 0, 0, 0);
        }
    }

    int rbase = rb*64 + wwr*32 + 4*hi;
    int col   = cb*64 + wwc*32 + l31;
    float sqc = sq[col];
    if (PASS == 1){
        float m = 0.f, mn = INFINITY;
        #pragma unroll
        for (int i = 0; i < 16; i++){
            int r = rbase + (i&3) + 8*(i>>2);
            float d2 = sq[r] + sqc - 2.f*acc[i];
            if (r != col) m = fmaxf(m, d2);
            if (r > col)  mn = fminf(mn, d2);
        }
        #pragma unroll
        for (int off = 32; off >= 1; off >>= 1){
            m  = fmaxf(m,  __shfl_down(m,  off));
            mn = fminf(mn, __shfl_down(mn, off));
        }
        __shared__ float wmax[4], wmin[4];
        if (lane == 0){ wmax[wv] = m; wmin[wv] = mn; }
        __syncthreads();
        if (tid == 0){
            tmax[rb*64 + cb] = fmaxf(fmaxf(wmax[0], wmax[1]), fmaxf(wmax[2], wmax[3]));
            tmin[rb*64 + cb] = fminf(fminf(wmin[0], wmin[1]), fminf(wmin[2], wmin[3]));
        }
    } else {
        #pragma unroll
        for (int i = 0; i < 16; i++){
            int r = rbase + (i&3) + 8*(i>>2);
            float d2 = sq[r] + sqc - 2.f*acc[i];
            if (r > col && d2 < tthr){
                unsigned idx = atomicAdd(ecnt, 1u);
                if (idx < EDGE_CAP){
                    edges[idx] = ((unsigned)r << 16) | (unsigned)col;  // dst<<16|src
                    atomicAdd(&deg[r], 1.0f);
                }
            }
        }
    }
}

// ---------------- X @ W via MFMA (bf16), raw output ------------------------
__global__ __launch_bounds__(256) void k_xw(const ushort* __restrict__ Ab,
        const ushort* __restrict__ Wb, float* __restrict__ XW, int M, int K){
    int rb = blockIdx.x, cb = blockIdx.y;     // (M/64, 4)
    __shared__ __align__(16) ushort As[64*64];
    __shared__ __align__(16) ushort Bs[64*64]; // Bs[n*64+kk] = W[k0+kk][cb*64+n]
    int tid = threadIdx.x, lane = tid & 63, wv = tid >> 6;
    int wwr = wv >> 1, wwc = wv & 1;
    int l31 = lane & 31, hi = lane >> 5;

    int arow0 = tid >> 3, ag = tid & 7;
    int arow1 = arow0 + 32;
    int da0 = arow0*64 + ((ag^(arow0&7))<<3);
    int da1 = arow1*64 + ((ag^(arow1&7))<<3);
    const size_t baseA = (size_t)rb*64*K;
    int kr = tid >> 2, ng = tid & 3;          // B: thread covers W[kr][ng*16..+15]

    float4 a0p = *(const float4*)(Ab + baseA + (size_t)arow0*K + ag*8);
    float4 a1p = *(const float4*)(Ab + baseA + (size_t)arow1*K + ag*8);
    float4 b0p = *(const float4*)(Wb + (size_t)kr*NH + cb*64 + ng*16);
    float4 b1p = *(const float4*)(Wb + (size_t)kr*NH + cb*64 + ng*16 + 8);

    v16f acc = {};
    int ra0 = (wwr*32 + l31)*64;
    int rb0 = (wwc*32 + l31)*64;
    int fr7a = (wwr*32 + l31) & 7;
    int fr7b = (wwc*32 + l31) & 7;
    int kg = kr >> 3, k7 = kr & 7;

    int NC = K >> 6;
    for (int c = 0; c < NC; c++){
        __syncthreads();
        *(float4*)&As[da0] = a0p; *(float4*)&As[da1] = a1p;
        const ushort* bw0 = (const ushort*)&b0p;
        const ushort* bw1 = (const ushort*)&b1p;
        #pragma unroll
        for (int j = 0; j < 8; j++){
            int nn = ng*16 + j;
            Bs[nn*64 + ((kg^(nn&7))<<3) + k7] = bw0[j];
        }
        #pragma unroll
        for (int j = 0; j < 8; j++){
            int nn = ng*16 + 8 + j;
            Bs[nn*64 + ((kg^(nn&7))<<3) + k7] = bw1[j];
        }
        __syncthreads();
        if (c + 1 < NC){
            int k0 = (c+1)*64;
            a0p = *(const float4*)(Ab + baseA + (size_t)arow0*K + k0 + ag*8);
            a1p = *(const float4*)(Ab + baseA + (size_t)arow1*K + k0 + ag*8);
            b0p = *(const float4*)(Wb + (size_t)(k0+kr)*NH + cb*64 + ng*16);
            b1p = *(const float4*)(Wb + (size_t)(k0+kr)*NH + cb*64 + ng*16 + 8);
        }
        #pragma unroll
        for (int ks = 0; ks < 4; ks++){
            int gq = ks*2 + hi;
            v8s a = *(const v8s*)&As[ra0 + ((gq^fr7a)<<3)];
            v8s b = *(const v8s*)&Bs[rb0 + ((gq^fr7b)<<3)];
            acc = __builtin_amdgcn_mfma_f32_32x32x16_bf16(a, b, acc, 0, 0, 0);
        }
    }
    int n  = cb*64 + wwc*32 + l31;
    int mb = rb*64 + wwr*32 + 4*hi;
    #pragma unroll
    for (int i = 0; i < 16; i++){
        int m = mb + (i&3) + 8*(i>>2);
        XW[(size_t)m*NH + n] = acc[i];
    }
}

// ---- fused GCN finish: edge-scan aggregation + relu + scorer --------------
__global__ __launch_bounds__(256) void k_gcnscore(const float* __restrict__ XW,
        const unsigned* __restrict__ edges, const unsigned* __restrict__ ecnt, int slot,
        const float* __restrict__ deg, const void* __restrict__ b,
        const void* __restrict__ Wn, const void* __restrict__ Wr, const void* __restrict__ bs,
        const unsigned* __restrict__ fb, const unsigned* __restrict__ fWn,
        const unsigned* __restrict__ fWr, const unsigned* __restrict__ fbs,
        float* __restrict__ Xn, float* __restrict__ s1, float* __restrict__ z){
    int row = blockIdx.x, t = threadIdx.x;
    __shared__ unsigned eL[256];
    __shared__ unsigned Esh;
    if (t == 0){ unsigned E0 = ecnt[slot]; Esh = (E0 > EDGE_CAP) ? EDGE_CAP : E0; }
    __syncthreads();
    unsigned E = Esh;
    float disr = 1.0f / sqrtf(deg[row]);
    float acc = disr * XW[row*NH + t];          // self term
    for (unsigned base = 0; base < E; base += 256){
        unsigned nchunk = E - base; if (nchunk > 256) nchunk = 256;
        __syncthreads();
        if (t < nchunk) eL[t] = edges[base + t];
        __syncthreads();
        for (unsigned j = 0; j < nchunk; j++){
            unsigned ed = eL[j];
            if ((int)(ed >> 16) == row){
                int src = ed & 0xFFFFu;
                acc += (1.0f / sqrtf(deg[src])) * XW[src*NH + t];
            }
        }
    }
    float xn = fmaxf(fmaf(disr, acc, ldf(b, t, (int)fb[0])), 0.f);
    Xn[row*NH + t] = xn;
    float a  = xn * ldf(Wn, t, (int)fWn[0]);
    float bb = xn * ldf(Wr, t, (int)fWr[0]);
    for (int off = 32; off >= 1; off >>= 1){ a += __shfl_down(a, off); bb += __shfl_down(bb, off); }
    __shared__ float ra[4], rbv[4];
    int w = t >> 6;
    if ((t & 63) == 0){ ra[w] = a; rbv[w] = bb; }
    __syncthreads();
    if (t == 0){
        s1[row] = ra[0]+ra[1]+ra[2]+ra[3];
        z[row]  = rbv[0]+rbv[1]+rbv[2]+rbv[3] + ldf(bs, 0, (int)fbs[0]);
    }
}

// ---------------- fused: scoredge + bisection top-k select + efilter -------
// Round 11 lesson: radix-histogram on clustered z -> 4096 same-address LDS
// atomics per pass (48 us). This version: 32-step ballot bisection (no
// atomics, distribution-independent) + prefix-sum output allocation.
__global__ __launch_bounds__(1024) void k_select(const float* __restrict__ z,
        const float* __restrict__ s1, int N, int k,
        const unsigned* __restrict__ eIn, unsigned* __restrict__ ecnt, int slotCur,
        unsigned* __restrict__ eOut, int slotOut,
        int* __restrict__ perm, float* __restrict__ svals,
        float* __restrict__ degN, int Nnext){
    __shared__ float zsh[4096];
    __shared__ int   rnk[4096];
    __shared__ uint  wcnt[16];
    __shared__ uint  wbase[16];
    __shared__ uint  sh[4];    // 0:cnt 1:cntGT 2:eqCnt 3:unused
    int t = threadIdx.x;
    int lane = t & 63, wv = t >> 6;
    for (int i = t; i < N; i += 1024){ zsh[i] = z[i]; rnk[i] = -1; }
    for (int i = t; i < Nnext; i += 1024) degN[i] = 1.0f;
    if (t == 0) sh[2] = 0u;
    __syncthreads();
    unsigned E = ecnt[slotCur]; if (E > EDGE_CAP) E = EDGE_CAP;
    for (unsigned e = t; e < E; e += 1024){
        unsigned ed = eIn[e];
        atomicAdd(&zsh[ed >> 16], s1[ed & 0xFFFFu]);
    }
    __syncthreads();
    // keys in registers (<=4 per thread)
    bool v0 = t < N,        v1 = t+1024 < N,  v2 = t+2048 < N,  v3 = t+3072 < N;
    uint c0 = v0 ? fcode(zsh[t])      : 0u;
    uint c1 = v1 ? fcode(zsh[t+1024]) : 0u;
    uint c2 = v2 ? fcode(zsh[t+2048]) : 0u;
    uint c3 = v3 ? fcode(zsh[t+3072]) : 0u;
    // bisection: largest T with count(key >= T) >= k  (T = k-th largest key)
    uint T = 0u;
    for (int bit = 31; bit >= 0; bit--){
        uint cand = T | (1u << bit);
        uint c = (uint)__popcll(__ballot(v0 && c0 >= cand))
               + (uint)__popcll(__ballot(v1 && c1 >= cand))
               + (uint)__popcll(__ballot(v2 && c2 >= cand))
               + (uint)__popcll(__ballot(v3 && c3 >= cand));
        if (lane == 0) wcnt[wv] = c;
        __syncthreads();
        if (t == 0){ uint s = 0; for (int i = 0; i < 16; i++) s += wcnt[i]; sh[0] = s; }
        __syncthreads();
        if (sh[0] >= (uint)k) T = cand;
        __syncthreads();
    }
    // strict-greater counts + prefix allocation
    ull b0 = __ballot(v0 && c0 > T), b1 = __ballot(v1 && c1 > T);
    ull b2 = __ballot(v2 && c2 > T), b3 = __ballot(v3 && c3 > T);
    uint t0 = (uint)__popcll(b0), t1 = (uint)__popcll(b1);
    uint t2 = (uint)__popcll(b2), t3 = (uint)__popcll(b3);
    if (lane == 0) wcnt[wv] = t0 + t1 + t2 + t3;
    __syncthreads();
    if (t == 0){
        uint s = 0;
        for (int i = 0; i < 16; i++){ wbase[i] = s; s += wcnt[i]; }
        sh[1] = s;   // cntGT
    }
    __syncthreads();
    uint cntGT = sh[1];
    uint rem = (uint)k - cntGT;
    ull ltm = ((ull)1 << lane) - 1;
    uint off = wbase[wv];
    if (v0 && c0 > T){ uint r = off + (uint)__popcll(b0 & ltm); int i = t;
        perm[r] = i; svals[r] = tanhf(zsh[i]); rnk[i] = (int)r; }
    off += t0;
    if (v1 && c1 > T){ uint r = off + (uint)__popcll(b1 & ltm); int i = t+1024;
        perm[r] = i; svals[r] = tanhf(zsh[i]); rnk[i] = (int)r; }
    off += t1;
    if (v2 && c2 > T){ uint r = off + (uint)__popcll(b2 & ltm); int i = t+2048;
        perm[r] = i; svals[r] = tanhf(zsh[i]); rnk[i] = (int)r; }
    off += t2;
    if (v3 && c3 > T){ uint r = off + (uint)__popcll(b3 & ltm); int i = t+3072;
        perm[r] = i; svals[r] = tanhf(zsh[i]); rnk[i] = (int)r; }
    // ties (== T): allocate the remaining 'rem' slots (tiny; atomics fine)
    #pragma unroll
    for (int j = 0; j < 4; j++){
        int i = t + j*1024;
        bool vv = (j==0) ? v0 : (j==1) ? v1 : (j==2) ? v2 : v3;
        uint cc = (j==0) ? c0 : (j==1) ? c1 : (j==2) ? c2 : c3;
        if (vv && cc == T){
            uint e = atomicAdd(&sh[2], 1u);
            if (e < rem){
                uint r = cntGT + e;
                perm[r] = i; svals[r] = tanhf(zsh[i]); rnk[i] = (int)r;
            }
        }
    }
    __syncthreads();
    // efilter: surviving edges renumbered into eOut + next-layer degree
    if (slotOut >= 0){
        for (unsigned e = t; e < E; e += 1024){
            unsigned ed = eIn[e];
            int nd = rnk[ed >> 16], ns = rnk[ed & 0xFFFFu];
            if (nd >= 0 && ns >= 0){
                unsigned idx = atomicAdd(&ecnt[slotOut], 1u);
                if (idx < EDGE_CAP){
                    eOut[idx] = ((unsigned)nd << 16) | (unsigned)ns;
                    atomicAdd(&degN[nd], 1.0f);
                }
            }
        }
    }
}

// ---------------- fused pool + readout: Pb (bf16) + col max/sum atomics ----
__global__ __launch_bounds__(256) void k_poolread(const float* __restrict__ Xn,
        const int* __restrict__ perm, const float* __restrict__ svals,
        ushort* __restrict__ Pb, int k, uint* __restrict__ maxU,
        float* __restrict__ sums, int layer){
    int b = blockIdx.x, t = threadIdx.x;
    float m = -INFINITY, s = 0.f;
    for (int r = b; r < k; r += 64){
        int p = perm[r];
        float v = Xn[p*NH + t] * svals[r];
        Pb[r*NH + t] = __bfloat16_as_ushort(__float2bfloat16(v));
        m = fmaxf(m, v); s += v;
    }
    atomicMax(&maxU[layer*NH + t], fcode(m));
    atomicAdd(&sums[layer*NH + t], s);
}

__global__ void k_writeout(const uint* __restrict__ maxU, const float* __restrict__ sums,
        float* __restrict__ out, float i1, float i2, float i3){
    int t = threadIdx.x;
    if (blockIdx.x == 0)
        out[t] = fdecode(maxU[t]) + fdecode(maxU[NH + t]) + fdecode(maxU[2*NH + t]);
    else
        out[NH + t] = sums[t]*i1 + sums[NH + t]*i2 + sums[2*NH + t]*i3;
}

// =======================================================================
extern "C" void kernel_launch(void* const* d_in, const int* in_sizes, int n_in,
                              void* d_out, int out_size, void* d_ws, size_t ws_size,
                              hipStream_t stream)
{
    const void* feature = d_in[0];
    const void* img     = d_in[1];
    const void* Wpos    = d_in[2];
    const void* bpos    = d_in[3];
    const void* W1 = d_in[4];  const void* b1 = d_in[5];
    const void* W2 = d_in[6];  const void* b2 = d_in[7];
    const void* W3 = d_in[8];  const void* b3 = d_in[9];
    const void* Wr1 = d_in[10]; const void* Wn1 = d_in[11]; const void* bs1 = d_in[12];
    const void* Wr2 = d_in[13]; const void* Wn2 = d_in[14]; const void* bs2 = d_in[15];
    const void* Wr3 = d_in[16]; const void* Wn3 = d_in[17]; const void* bs3 = d_in[18];

    char* w = (char*)d_ws;
    auto alloc = [&](size_t bytes)->char*{ char* p = w; w += (bytes + 255) & ~(size_t)255; return p; };
    ushort*   Xb    = (ushort*)  alloc((size_t)NN*DIN*2);   // 4 MB
    float*    Xn    = (float*)   alloc((size_t)NN*NH*4);    // 4 MB
    float*    XW    = (float*)   alloc((size_t)NN*NH*4);    // 4 MB
    ushort*   Pb    = (ushort*)  alloc((size_t)KL1*NH*2);   // 1.5 MB pooled bf16
    ushort*   Wb    = (ushort*)  alloc((size_t)262144*2);   // 0.5 MB W1|W2|W3 bf16
    unsigned* E0    = (unsigned*)alloc((size_t)EDGE_CAP*4); // 3 MB
    unsigned* E1    = (unsigned*)alloc((size_t)EDGE_CAP*4); // 3 MB
    float*    tmax  = (float*)   alloc(4096*4);             // per-tile max d2
    float*    tmin  = (float*)   alloc(4096*4);             // per-tile min d2 (r>c)
    float*    sq    = (float*)   alloc(NN*4);
    float*    degA  = (float*)   alloc(NN*4);
    float*    degB  = (float*)   alloc(NN*4);
    float*    s1    = (float*)   alloc(NN*4);
    float*    z     = (float*)   alloc(NN*4);
    int*      perm  = (int*)     alloc(NN*4);
    float*    svals = (float*)   alloc(NN*4);
    unsigned* ecnt  = (unsigned*)alloc(256);
    unsigned* dflag = (unsigned*)alloc(256);
    uint*     maxU  = (uint*)    alloc(768*4);
    float*    sums  = (float*)   alloc(768*4);
    (void)ws_size;

    DtIn da;
    for (int i = 0; i < 19; i++){ da.p[i] = d_in[i]; da.n[i] = in_sizes[i]; }
    k_initall<<<16, 256, 0, stream>>>(da, dflag, degA, maxU, sums, ecnt, tmax, tmin);
    k_prep<<<NN + 64, 512, 0, stream>>>(feature, img, Wpos, bpos, W1, W2, W3,
            dflag, Xb, sq, Wb);
    dim3 gg(64, 64);
    k_gram<1><<<gg, 256, 0, stream>>>(Xb, sq, tmax, tmin, ecnt, E0, degA);
    k_gram<2><<<gg, 256, 0, stream>>>(Xb, sq, tmax, tmin, ecnt, E0, degA);

    // ---------------- layer 1 (N=4096 -> k=3072) ----------------
    k_xw<<<dim3(64,4), 256, 0, stream>>>(Xb, Wb, XW, NN, DIN);
    k_gcnscore<<<NN, 256, 0, stream>>>(XW, E0, ecnt, 0, degA, b1, Wn1, Wr1, bs1,
            dflag+5, dflag+11, dflag+10, dflag+12, Xn, s1, z);
    k_select<<<1, 1024, 0, stream>>>(z, s1, NN, KL1, E0, ecnt, 0, E1, 1,
            perm, svals, degB, KL1);
    k_poolread<<<64, 256, 0, stream>>>(Xn, perm, svals, Pb, KL1, maxU, sums, 0);

    // ---------------- layer 2 (N=3072 -> k=2304) ----------------
    k_xw<<<dim3(48,4), 256, 0, stream>>>(Pb, Wb + 131072, XW, KL1, NH);
    k_gcnscore<<<KL1, 256, 0, stream>>>(XW, E1, ecnt, 1, degB, b2, Wn2, Wr2, bs2,
            dflag+7, dflag+14, dflag+13, dflag+15, Xn, s1, z);
    k_select<<<1, 1024, 0, stream>>>(z, s1, KL1, KL2, E1, ecnt, 1, E0, 2,
            perm, svals, degA, KL2);
    k_poolread<<<64, 256, 0, stream>>>(Xn, perm, svals, Pb, KL2, maxU, sums, 1);

    // ---------------- layer 3 (N=2304 -> k=1728) ----------------
    k_xw<<<dim3(36,4), 256, 0, stream>>>(Pb, Wb + 196608, XW, KL2, NH);
    k_gcnscore<<<KL2, 256, 0, stream>>>(XW, E0, ecnt, 2, degA, b3, Wn3, Wr3, bs3,
            dflag+9, dflag+17, dflag+16, dflag+18, Xn, s1, z);
    k_select<<<1, 1024, 0, stream>>>(z, s1, KL2, KL3, E0, ecnt, 2, (unsigned*)nullptr, -1,
            perm, svals, degB, 0);
    k_poolread<<<64, 256, 0, stream>>>(Xn, perm, svals, Pb, KL3, maxU, sums, 2);

    k_writeout<<<2, 256, 0, stream>>>(maxU, sums, (float*)d_out,
            1.0f/KL1, 1.0f/KL2, 1.0f/KL3);
}